// Round 1
// baseline (392.104 us; speedup 1.0000x reference)
//
#include <hip/hip_runtime.h>
#include <hip/hip_bf16.h>

typedef float        f32x4  __attribute__((ext_vector_type(4)));
typedef __bf16       bf16x8 __attribute__((ext_vector_type(8)));
typedef unsigned int u32x4  __attribute__((ext_vector_type(4)));

// ws layout
#define S1_OFF   0u
#define S1_BYTES (64u * 8192u * 32u)            // 16,777,216 B (bitpacked s1: [t][b][256 bits])
#define WB_OFF   S1_BYTES
#define WB_BYTES (4u * 8u * 4u * 3u * 1024u)    // 393,216 B (W_h 3-way bf16 splits, fragment-linear)
#define PART_OFF (WB_OFF + WB_BYTES)            // 17,170,432 B
#define NPART    256

static __device__ __forceinline__ float clamp01(float v) {
    return fminf(fmaxf(v, 0.0f), 1.0f);
}
static __device__ __forceinline__ unsigned short f2bf(float f) {  // RNE float->bf16
    unsigned int u = __builtin_bit_cast(unsigned int, f);
    u += 0x7FFFu + ((u >> 16) & 1u);
    return (unsigned short)(u >> 16);
}
static __device__ __forceinline__ float bf2f(unsigned short b) {
    unsigned int u = ((unsigned int)b) << 16;
    return __builtin_bit_cast(float, u);
}

// ---------------------------------------------------------------------------
// k0: split W_h into 3 bf16 parts (hi+mid+lo ~= fp32) and store in
// fragment-linear order for mfma_f32_16x16x32_bf16 B-operand:
//   B[k=d][col=h] ; lane = (h&15) | (((d>>3)&3)<<4) ; elem j = d&7
//   frag id (per 64-col block nb): ((ks*4 + nfq)*3 + sp), 1024 B each
// ---------------------------------------------------------------------------
__global__ void k0_prepW(const float* __restrict__ W_h,
                         unsigned short* __restrict__ WB) {
    int id = blockIdx.x * 256 + threadIdx.x;   // 65536 = h*256 + d
    int h = id >> 8, d = id & 255;
    float w = W_h[id];
    unsigned short s0 = f2bf(w);
    float r1 = w - bf2f(s0);
    unsigned short s1 = f2bf(r1);
    float r2 = r1 - bf2f(s1);
    unsigned short s2 = f2bf(r2);
    int nb = h >> 6, nfq = (h >> 4) & 3, colL = h & 15;
    int ks = d >> 5, lsel = (d >> 3) & 3, j = d & 7;
    int lane = colL | (lsel << 4);
    size_t base = (size_t)nb * 49152u + (size_t)((ks * 4 + nfq) * 3) * 512u
                + (size_t)lane * 8u + (size_t)j;       // u16 units
    WB[base]        = s0;
    WB[base + 512]  = s1;
    WB[base + 1024] = s2;
}

// ---------------------------------------------------------------------------
// k1: cur_in = x_t @ W_in^T + b_in  (fp32), then 64-step layer-1 recurrence,
// emit s1 bitpacked via __ballot.  Block: 32 batches x 256 h, 256 threads.
// Thread: lane=tid&63, grp=tid>>6 ; owns h = {lane, lane+64, lane+128, lane+192}
// and 8 batches (grp*8..grp*8+7).  Wave spans one grp -> LDS reads broadcast.
// ---------------------------------------------------------------------------
__global__ __launch_bounds__(256) void k1_layer1(
    const float* __restrict__ x, const float* __restrict__ W_in,
    const float* __restrict__ b_in, const float* __restrict__ beta_in,
    const float* __restrict__ thr_in, unsigned long long* __restrict__ S1) {
    __shared__ float Xs[32][256];
    int tid = threadIdx.x;
    int b0 = blockIdx.x * 32;
    #pragma unroll 4
    for (int bb = 0; bb < 32; ++bb)
        Xs[bb][tid] = x[((size_t)(b0 + bb) * 256 + tid) * 64];  // x[0,b,d,0]
    __syncthreads();

    int lane = tid & 63, grp = tid >> 6;
    int   h[4]; float bi[4], b1[4], th[4];
    #pragma unroll
    for (int i = 0; i < 4; ++i) {
        h[i]  = i * 64 + lane;
        bi[i] = b_in[h[i]];
        b1[i] = clamp01(beta_in[h[i]]);
        th[i] = thr_in[h[i]];
    }
    float cur[4][8];
    #pragma unroll
    for (int i = 0; i < 4; ++i)
        #pragma unroll
        for (int bb = 0; bb < 8; ++bb) cur[i][bb] = bi[i];

    #pragma unroll 2
    for (int d4 = 0; d4 < 64; ++d4) {
        f32x4 w[4];
        #pragma unroll
        for (int i = 0; i < 4; ++i)
            w[i] = *(const f32x4*)(W_in + (size_t)h[i] * 256 + d4 * 4);
        #pragma unroll
        for (int bb = 0; bb < 8; ++bb) {
            f32x4 xv = *(const f32x4*)(&Xs[grp * 8 + bb][d4 * 4]);
            #pragma unroll
            for (int i = 0; i < 4; ++i)
                cur[i][bb] += w[i][0]*xv[0] + w[i][1]*xv[1] + w[i][2]*xv[2] + w[i][3]*xv[3];
        }
    }

    float m1[4][8];
    #pragma unroll
    for (int i = 0; i < 4; ++i)
        #pragma unroll
        for (int bb = 0; bb < 8; ++bb) m1[i][bb] = 0.0f;

    #pragma unroll 1
    for (int t = 0; t < 64; ++t) {
        #pragma unroll
        for (int i = 0; i < 4; ++i) {
            #pragma unroll
            for (int bb = 0; bb < 8; ++bb) {
                float mm = m1[i][bb];
                float rst = (mm > th[i]) ? th[i] : 0.0f;   // r1*thr (r1 uses old m1)
                mm = b1[i] * mm + cur[i][bb] - rst;
                m1[i][bb] = mm;
                unsigned long long bal = __ballot(mm > th[i]);  // s1 bits, d = i*64+lane
                if (lane == 0)
                    S1[((size_t)t * 8192 + (size_t)(b0 + grp * 8 + bb)) * 4 + i] = bal;
            }
        }
    }
}

// ---------------------------------------------------------------------------
// k2: fused 64-step loop: cur_h = s1 @ W_h^T (triple-bf16 MFMA) + layer-2
// recurrence + layer-3 linear accumulation.  Grid (64,4): x = 128-batch tile,
// y = 64-col block nb.  256 thr = 4 waves; wave tile M=64 x N=32.
// No barriers inside the t-loop; W splits in LDS; m2 in registers.
// ---------------------------------------------------------------------------
__global__ __launch_bounds__(256) void k2_main(
    const unsigned int* __restrict__ S1,
    const u32x4* __restrict__ WB,
    const float* __restrict__ b_h, const float* __restrict__ beta_h,
    const float* __restrict__ thr_h, const float* __restrict__ W_o,
    const float* __restrict__ beta_o, float* __restrict__ partials) {
    __shared__ u32x4 Blds[6144];   // 96 KB
    __shared__ float wred[4];
    int tid = threadIdx.x, lane = tid & 63, wid = tid >> 6;

    const u32x4* src = WB + (size_t)blockIdx.y * 6144;
    #pragma unroll
    for (int k = 0; k < 24; ++k) Blds[k * 256 + tid] = src[k * 256 + tid];
    __syncthreads();

    int mh = wid & 1, nh = wid >> 1;
    int colL = lane & 15, ksel = lane >> 4;
    int rowbase = blockIdx.x * 128 + mh * 64 + colL;

    float thr[2], b2[2], wo[2], bh[2];
    #pragma unroll
    for (int nf = 0; nf < 2; ++nf) {
        int hcol = blockIdx.y * 64 + nh * 32 + nf * 16 + colL;
        thr[nf] = thr_h[hcol];
        b2[nf]  = clamp01(beta_h[hcol]);
        wo[nf]  = W_o[hcol];
        bh[nf]  = b_h[hcol];
    }
    float b3 = clamp01(beta_o[0]);

    const f32x4 zf = {0.0f, 0.0f, 0.0f, 0.0f};
    f32x4 m2[4][2];
    #pragma unroll
    for (int m = 0; m < 4; ++m)
        #pragma unroll
        for (int nf = 0; nf < 2; ++nf) m2[m][nf] = zf;
    float acc3 = 0.0f;

    #pragma unroll 1
    for (int t = 0; t < 64; ++t) {
        f32x4 acc[4][2];
        #pragma unroll
        for (int m = 0; m < 4; ++m)
            #pragma unroll
            for (int nf = 0; nf < 2; ++nf) acc[m][nf] = zf;

        const unsigned int* Srow = S1 + (size_t)t * 65536;  // 8192 rows * 8 u32
        #pragma unroll
        for (int ks = 0; ks < 8; ++ks) {
            bf16x8 a[4];
            #pragma unroll
            for (int m = 0; m < 4; ++m) {
                unsigned int w  = Srow[(rowbase + m * 16) * 8 + ks];
                unsigned int by = (w >> (ksel * 8)) & 0xFFu;
                u32x4 uw;
                uw[0] = ((by & 1u)  ? 0x3F80u : 0u) | ((by & 2u)   ? 0x3F800000u : 0u);
                uw[1] = ((by & 4u)  ? 0x3F80u : 0u) | ((by & 8u)   ? 0x3F800000u : 0u);
                uw[2] = ((by & 16u) ? 0x3F80u : 0u) | ((by & 32u)  ? 0x3F800000u : 0u);
                uw[3] = ((by & 64u) ? 0x3F80u : 0u) | ((by & 128u) ? 0x3F800000u : 0u);
                a[m] = __builtin_bit_cast(bf16x8, uw);
            }
            #pragma unroll
            for (int nf = 0; nf < 2; ++nf) {
                int nfq = nh * 2 + nf;
                #pragma unroll
                for (int sp = 0; sp < 3; ++sp) {
                    bf16x8 bfr = __builtin_bit_cast(bf16x8,
                        Blds[((ks * 4 + nfq) * 3 + sp) * 64 + lane]);
                    #pragma unroll
                    for (int m = 0; m < 4; ++m)
                        acc[m][nf] = __builtin_amdgcn_mfma_f32_16x16x32_bf16(
                            a[m], bfr, acc[m][nf], 0, 0, 0);
                }
            }
        }
        // layer-2 recurrence + layer-3 linear accumulation
        float sum = 0.0f;
        #pragma unroll
        for (int m = 0; m < 4; ++m)
            #pragma unroll
            for (int nf = 0; nf < 2; ++nf)
                #pragma unroll
                for (int r = 0; r < 4; ++r) {
                    float cv  = acc[m][nf][r] + bh[nf];     // cur_h
                    float mm  = m2[m][nf][r];
                    float rst = (mm > thr[nf]) ? thr[nf] : 0.0f;  // r2 uses old m2
                    mm = b2[nf] * mm + cv - rst;
                    m2[m][nf][r] = mm;
                    if (mm > thr[nf]) sum += wo[nf];        // s2 * w_o
                }
        acc3 = b3 * acc3 + sum;   // m3 is linear: final = sum_t b3^(63-t) * cur_o[t]
    }

    #pragma unroll
    for (int off = 32; off; off >>= 1) acc3 += __shfl_xor(acc3, off);
    if (lane == 0) wred[wid] = acc3;
    __syncthreads();
    if (tid == 0)
        partials[blockIdx.y * 64 + blockIdx.x] = (wred[0] + wred[1]) + (wred[2] + wred[3]);
}

// ---------------------------------------------------------------------------
// k3: deterministic final reduction + bias/geometric term
// ---------------------------------------------------------------------------
__global__ void k3_final(const float* __restrict__ partials,
                         const float* __restrict__ b_o,
                         const float* __restrict__ beta_o,
                         float* __restrict__ out) {
    __shared__ float wred[4];
    int tid = threadIdx.x, lane = tid & 63, wid = tid >> 6;
    float v = partials[tid];
    #pragma unroll
    for (int off = 32; off; off >>= 1) v += __shfl_xor(v, off);
    if (lane == 0) wred[wid] = v;
    __syncthreads();
    if (tid == 0) {
        float total = (wred[0] + wred[1]) + (wred[2] + wred[3]);
        float b3 = clamp01(beta_o[0]);
        float geo = 0.0f, p = 1.0f;
        #pragma unroll 1
        for (int i = 0; i < 64; ++i) { geo += p; p *= b3; }
        out[0] = total / 8192.0f + b_o[0] * geo;
    }
}

extern "C" void kernel_launch(void* const* d_in, const int* in_sizes, int n_in,
                              void* d_out, int out_size, void* d_ws, size_t ws_size,
                              hipStream_t stream) {
    const float* x       = (const float*)d_in[0];
    const float* W_in    = (const float*)d_in[1];
    const float* b_in    = (const float*)d_in[2];
    const float* beta_in = (const float*)d_in[3];
    const float* thr_in  = (const float*)d_in[4];
    const float* W_h     = (const float*)d_in[5];
    const float* b_h     = (const float*)d_in[6];
    const float* beta_h  = (const float*)d_in[7];
    const float* thr_h   = (const float*)d_in[8];
    const float* W_o     = (const float*)d_in[9];
    const float* b_o     = (const float*)d_in[10];
    const float* beta_o  = (const float*)d_in[11];
    (void)in_sizes; (void)n_in; (void)out_size; (void)ws_size;

    char* ws = (char*)d_ws;
    unsigned long long* S1 = (unsigned long long*)(ws + S1_OFF);
    unsigned short*     WB = (unsigned short*)(ws + WB_OFF);
    float*        partials = (float*)(ws + PART_OFF);

    k0_prepW <<<256, 256, 0, stream>>>(W_h, WB);
    k1_layer1<<<256, 256, 0, stream>>>(x, W_in, b_in, beta_in, thr_in, S1);
    k2_main  <<<dim3(64, 4), 256, 0, stream>>>((const unsigned int*)S1, (const u32x4*)WB,
                                               b_h, beta_h, thr_h, W_o, beta_o, partials);
    k3_final <<<1, 256, 0, stream>>>(partials, b_o, beta_o, (float*)d_out);
}